// Round 8
// baseline (919.195 us; speedup 1.0000x reference)
//
#include <hip/hip_runtime.h>

typedef __attribute__((ext_vector_type(8)))  short short8;   // 8 bf16 (4 VGPRs)
typedef __attribute__((ext_vector_type(16))) float f32x16;   // 32x32 MFMA acc
typedef unsigned short ushort_t;
typedef unsigned int uint32;
typedef unsigned long long uint64;

#define NROWS 8192
#define NCODE 8192
#define DIM   512

// error window: |(d'+xn) - D| <= 2*2.004*2^-8*sqrt(xn*enmax)  (bf16 RNE + C-S)
// W = 2x that + guard (covers fp32 epilogue rounding)
#define W_COEF  0.032f
#define W_GUARD 0.6f

// ---------------- d_out layout (floats) ----------------
#define OUT_Q      0
#define OUT_LOSS   4194304
#define OUT_IDX    4194305
#define OUT_MIND   4202497
#define OUT_COMMIT 4210689
// masks[8192][64][2] u64 live in d_out floats [2097152, 4194304) between
// vq (write) and refine (read); refine overwrites with qout afterwards.

// ---------------- ws layout (floats) ----------------
#define WS_ENORM  0           // 8192
#define WS_XNORM  8192        // 8192
#define WS_ENMAX  16384       // 1
#define WS_LPART  16448       // 2048
#define WS_MINS   32768       // mins[8192][64] f32 = 524288 floats
#define WS_BHI    557056      // 4,194,304 ushorts (8.39 MB)

// ===========================================================================
__device__ inline uint32 bf16_rne(float f) {
    uint32 u = __float_as_uint(f);
    return (u + 0x7FFFu + ((u >> 16) & 1u)) >> 16;
}

__device__ inline void gload16(const ushort_t* g, ushort_t* l) {
    __builtin_amdgcn_global_load_lds(
        (const __attribute__((address_space(1))) void*)g,
        (__attribute__((address_space(3))) void*)l, 16, 0, 0);
}

// ===========================================================================
// Kernel 1: convert x and codebook to fragment-ordered bf16 HI tiles only.
// Tile = 128 rows x 32 k, 8 KB, 8 chunks of 1 KB: chunk c = r32*2 + k16;
// lane L holds row = r32*32 + (L&31), k = k16*16 + (L>>5)*8 + j.
// Also exact fp32 row norms (xnorm for inputs, enorm for codebook).
__global__ __launch_bounds__(256) void conv_kernel(const float* __restrict__ x,
                                                   const float* __restrict__ cb,
                                                   ushort_t* __restrict__ ahi,
                                                   ushort_t* __restrict__ bhi,
                                                   float* __restrict__ xnorm,
                                                   float* __restrict__ enorm) {
    int gid  = blockIdx.x * 256 + threadIdx.x;   // 0..1048575
    bool isA = gid < 524288;
    int g    = isA ? gid : gid - 524288;
    int row  = g >> 6;
    int lane = g & 63;
    int k0   = lane * 8;
    const float* src = (isA ? x : cb) + (size_t)row * DIM + k0;
    float v[8];
    *(float4*)&v[0] = *(const float4*)src;
    *(float4*)&v[4] = *(const float4*)(src + 4);
    float s = 0.0f;
    uint32 h[8];
    #pragma unroll
    for (int i = 0; i < 8; ++i) {
        s += v[i] * v[i];
        h[i] = bf16_rne(v[i]);
    }
    int tile = (row >> 7) * 16 + (k0 >> 5);
    int rp = row & 127, kp = k0 & 31;
    int c  = (rp >> 5) * 2 + (kp >> 4);
    int L  = (rp & 31) + (((kp >> 3) & 1) << 5);
    size_t off = (size_t)tile * 4096 + c * 512 + L * 8;   // ushort units
    uint4 ph;
    ph.x = h[0] | (h[1] << 16); ph.y = h[2] | (h[3] << 16);
    ph.z = h[4] | (h[5] << 16); ph.w = h[6] | (h[7] << 16);
    if (isA) *(uint4*)(ahi + off) = ph;
    else     *(uint4*)(bhi + off) = ph;
    #pragma unroll
    for (int o = 32; o > 0; o >>= 1) s += __shfl_down(s, o);
    if (lane == 0) { if (isA) xnorm[row] = s; else enorm[row] = s; }
}

// ===========================================================================
// Kernel 1b: en_max = max over codebook norms (for the prune bound).
__global__ __launch_bounds__(256) void prep_kernel(const float* __restrict__ enorm,
                                                   float* __restrict__ enmax) {
    __shared__ float sm[256];
    float m = 0.0f;
    for (int i = threadIdx.x; i < NCODE; i += 256) m = fmaxf(m, enorm[i]);
    sm[threadIdx.x] = m;
    __syncthreads();
    #pragma unroll
    for (int o = 128; o > 0; o >>= 1) {
        if (threadIdx.x < o) sm[threadIdx.x] = fmaxf(sm[threadIdx.x], sm[threadIdx.x + o]);
        __syncthreads();
    }
    if (threadIdx.x == 0) enmax[0] = sm[0];
}

// ===========================================================================
// Kernel 2 (R8): hi-only GEMM, K-step 32, triple-buffered B LDS + A direct.
// R7's vmcnt(2) was ORDER-FRAGILE: it assumed the 2 newest outstanding vmem
// ops were stageB(n+2), but the compiler reorders independent loads within
// a region. R8 counts REGIONS, not ops: cross-region issue order IS pinned
// by the asm memory clobbers, and each step issues exactly 6 vmem ops, so
// vmcnt(4) at step end completes everything from all PRIOR regions (buf n+1
// guaranteed landed) no matter how loads were ordered inside a region.
// Prologue does a one-time full drain (order-free). FB register readiness
// is the compiler's own waitcnt insertion (it tracks its loads).
// Block 256 rows x 128 cols, 4 waves row-stacked, wave tile 64x128 acc[2][4].
// Grid 2048 = 32 bx x 64 by; XCD q&7 hosts bx band (1 MB A L2-resident).
struct AF { short8 a00, a01, a10, a11; };   // a{ti}{p}

__global__ __launch_bounds__(256, 2) void vq_mfma_kernel(
        const ushort_t* __restrict__ ahi, const ushort_t* __restrict__ bhi,
        const float* __restrict__ xnorm, const float* __restrict__ enorm,
        const float* __restrict__ enmax,
        float* __restrict__ mins, uint64* __restrict__ masks) {
    __shared__ __align__(16) ushort_t smem[12288];   // 3 x 8 KB B buffers

    const int tid  = threadIdx.x;            // 0..255
    const int wave = tid >> 6, lane = tid & 63;
    const int l31  = lane & 31, half = lane >> 5;
    const int q  = blockIdx.x;
    const int bx = (q & 7) * 4 + (q >> 9);   // 0..31 (256-row block), XCD=q&7
    const int by = (q >> 3) & 63;            // 0..63 (128-col slice)
    const int l8 = lane * 8;

    f32x16 acc[2][4];
    #pragma unroll
    for (int i = 0; i < 2; ++i)
        #pragma unroll
        for (int j = 0; j < 4; ++j)
            #pragma unroll
            for (int r = 0; r < 16; ++r) acc[i][j][r] = 0.0f;

    // A row-tile base pointers: rt = bx*8 + wave*2 + ti
    // conv layout: addr(rt, kk) = (rt>>2)*65536 + (rt&3)*1024 + (kk>>1)*4096
    //                           + (kk&1)*512 + l8   (ushort units)
    const int rt0 = bx * 8 + wave * 2, rt1 = rt0 + 1;
    const ushort_t* pa0 = ahi + ((size_t)(rt0 >> 2)) * 65536 + (rt0 & 3) * 1024 + l8;
    const ushort_t* pa1 = ahi + ((size_t)(rt1 >> 2)) * 65536 + (rt1 & 3) * 1024 + l8;
    // B tile base: step n occupies [by*16+n]*4096 ushorts (full 8 KB tile)
    const ushort_t* pb = bhi + ((size_t)by * 16) * 4096;

    // stage B step nn into buffer nn%3 (8 KB, 2 gload16/thread)
    auto stageB = [&](int nn) {
        ushort_t* S = smem + (nn % 3) * 4096;
        gload16(pb + (size_t)nn * 4096 + tid * 8,        S + tid * 8);
        gload16(pb + (size_t)nn * 4096 + 2048 + tid * 8, S + 2048 + tid * 8);
    };
    auto loadA = [&](AF& F, int nn) {
        F.a00 = *(const short8*)(pa0 + (size_t)nn * 4096);
        F.a01 = *(const short8*)(pa0 + (size_t)nn * 4096 + 512);
        F.a10 = *(const short8*)(pa1 + (size_t)nn * 4096);
        F.a11 = *(const short8*)(pa1 + (size_t)nn * 4096 + 512);
    };

#define STEP(n, CUR, NXT) do {                                                \
    if ((n) + 1 < 16) loadA(NXT, (n) + 1);        /* 4 vmem */               \
    if ((n) + 2 < 16) stageB((n) + 2);            /* 2 vmem, buf (n+2)%3 */  \
    const ushort_t* S = smem + ((n) % 3) * 4096;                              \
    short8 b0 = *(const short8*)&S[0 * 1024 + l8];                            \
    short8 b1 = *(const short8*)&S[1 * 1024 + l8];                            \
    short8 b2 = *(const short8*)&S[2 * 1024 + l8];                            \
    short8 b3 = *(const short8*)&S[3 * 1024 + l8];                            \
    asm volatile("s_waitcnt lgkmcnt(0)" ::: "memory");                        \
    __builtin_amdgcn_sched_barrier(0);                                        \
    __builtin_amdgcn_s_setprio(1);                                            \
    acc[0][0] = __builtin_amdgcn_mfma_f32_32x32x16_bf16(CUR.a00, b0, acc[0][0], 0, 0, 0); \
    acc[0][1] = __builtin_amdgcn_mfma_f32_32x32x16_bf16(CUR.a00, b1, acc[0][1], 0, 0, 0); \
    acc[0][2] = __builtin_amdgcn_mfma_f32_32x32x16_bf16(CUR.a00, b2, acc[0][2], 0, 0, 0); \
    acc[0][3] = __builtin_amdgcn_mfma_f32_32x32x16_bf16(CUR.a00, b3, acc[0][3], 0, 0, 0); \
    acc[1][0] = __builtin_amdgcn_mfma_f32_32x32x16_bf16(CUR.a10, b0, acc[1][0], 0, 0, 0); \
    acc[1][1] = __builtin_amdgcn_mfma_f32_32x32x16_bf16(CUR.a10, b1, acc[1][1], 0, 0, 0); \
    acc[1][2] = __builtin_amdgcn_mfma_f32_32x32x16_bf16(CUR.a10, b2, acc[1][2], 0, 0, 0); \
    acc[1][3] = __builtin_amdgcn_mfma_f32_32x32x16_bf16(CUR.a10, b3, acc[1][3], 0, 0, 0); \
    __builtin_amdgcn_s_setprio(0);                                            \
    short8 c0 = *(const short8*)&S[0 * 1024 + 512 + l8];                      \
    short8 c1 = *(const short8*)&S[1 * 1024 + 512 + l8];                      \
    short8 c2 = *(const short8*)&S[2 * 1024 + 512 + l8];                      \
    short8 c3 = *(const short8*)&S[3 * 1024 + 512 + l8];                      \
    asm volatile("s_waitcnt lgkmcnt(0)" ::: "memory");                        \
    __builtin_amdgcn_sched_barrier(0);                                        \
    __builtin_amdgcn_s_setprio(1);                                            \
    acc[0][0] = __builtin_amdgcn_mfma_f32_32x32x16_bf16(CUR.a01, c0, acc[0][0], 0, 0, 0); \
    acc[0][1] = __builtin_amdgcn_mfma_f32_32x32x16_bf16(CUR.a01, c1, acc[0][1], 0, 0, 0); \
    acc[0][2] = __builtin_amdgcn_mfma_f32_32x32x16_bf16(CUR.a01, c2, acc[0][2], 0, 0, 0); \
    acc[0][3] = __builtin_amdgcn_mfma_f32_32x32x16_bf16(CUR.a01, c3, acc[0][3], 0, 0, 0); \
    acc[1][0] = __builtin_amdgcn_mfma_f32_32x32x16_bf16(CUR.a11, c0, acc[1][0], 0, 0, 0); \
    acc[1][1] = __builtin_amdgcn_mfma_f32_32x32x16_bf16(CUR.a11, c1, acc[1][1], 0, 0, 0); \
    acc[1][2] = __builtin_amdgcn_mfma_f32_32x32x16_bf16(CUR.a11, c2, acc[1][2], 0, 0, 0); \
    acc[1][3] = __builtin_amdgcn_mfma_f32_32x32x16_bf16(CUR.a11, c3, acc[1][3], 0, 0, 0); \
    __builtin_amdgcn_s_setprio(0);                                            \
    /* region-counted wait: <=4 outstanding => ALL prior regions complete */  \
    if ((n) + 2 < 16) { asm volatile("s_waitcnt vmcnt(4)" ::: "memory"); }    \
    else              { asm volatile("s_waitcnt vmcnt(0)" ::: "memory"); }    \
    asm volatile("s_barrier" ::: "memory");                                   \
} while (0)

    AF FA, FB;
    // prologue: order-free full drain (one-time), then region-pipelined loop
    stageB(0);
    stageB(1);
    loadA(FA, 0);
    asm volatile("s_waitcnt vmcnt(0)" ::: "memory");   // buf0, buf1, FA landed
    asm volatile("s_barrier" ::: "memory");

    #pragma unroll
    for (int n = 0; n < 16; ++n) {
        if (n & 1) STEP(n, FB, FA);
        else       STEP(n, FA, FB);
    }
#undef STEP

    // ---- epilogue: per row emit f32 slice-min + 128-bit candidate mask ----
    const float enm = enmax[0];
    float en[4];
    #pragma unroll
    for (int tj = 0; tj < 4; ++tj) en[tj] = enorm[by * 128 + tj * 32 + l31];

    #pragma unroll
    for (int ti = 0; ti < 2; ++ti)
        #pragma unroll
        for (int r = 0; r < 16; ++r) {
            const int row = bx * 256 + wave * 64 + ti * 32
                          + (r & 3) + 8 * (r >> 2) + 4 * half;
            const float xn = xnorm[row];
            const float W  = W_COEF * sqrtf(xn * enm) + W_GUARD;
            const float d0 = en[0] - 2.0f * acc[ti][0][r];
            const float d1 = en[1] - 2.0f * acc[ti][1][r];
            const float d2 = en[2] - 2.0f * acc[ti][2][r];
            const float d3 = en[3] - 2.0f * acc[ti][3][r];
            float m = fminf(fminf(d0, d1), fminf(d2, d3));
            #pragma unroll
            for (int o = 1; o < 32; o <<= 1) m = fminf(m, __shfl_xor(m, o));
            const float t = m + W;
            const uint64 b0m = __ballot(d0 <= t);
            const uint64 b1m = __ballot(d1 <= t);
            const uint64 b2m = __ballot(d2 <= t);
            const uint64 b3m = __ballot(d3 <= t);
            if (l31 == 0) {
                const int sh = half * 32;
                const uint64 m0 = ((b0m >> sh) & 0xFFFFFFFFull)
                                | (((b1m >> sh) & 0xFFFFFFFFull) << 32);
                const uint64 m1 = ((b2m >> sh) & 0xFFFFFFFFull)
                                | (((b3m >> sh) & 0xFFFFFFFFull) << 32);
                const size_t rec = (size_t)row * 64 + by;
                mins[rec] = m;
                masks[rec * 2]     = m0;
                masks[rec * 2 + 1] = m1;
            }
        }
}

// ===========================================================================
// Kernel 3: refine + finish fused. Per row (one wave): gmin over 64 slice
// mins; window thr = gmin + W; exact fp32 wave-coop distance for each
// candidate column from the ballot masks (~3-8/row); then gather the winning
// codebook row -> qout, exact ||x-e||^2 -> mind, block loss partial.
__global__ __launch_bounds__(256) void refine_kernel(
        const float* __restrict__ x, const float* __restrict__ cb,
        const float* __restrict__ xnorm, const float* __restrict__ enorm,
        const float* __restrict__ enmax, const float* __restrict__ mins,
        const uint64* __restrict__ masks, float* __restrict__ out_idx,
        float* __restrict__ qout, float* __restrict__ out_mind,
        float* __restrict__ lpart) {
    __shared__ float sred[4];
    const int wave = threadIdx.x >> 6, lane = threadIdx.x & 63;
    const int row  = blockIdx.x * 4 + wave;

    const float4* x4 = (const float4*)(x + (size_t)row * DIM);
    const float4 xa = x4[lane], xb = x4[lane + 64];
    const float  xn = xnorm[row];

    float m = mins[(size_t)row * 64 + lane];
    float gmin = m;
    #pragma unroll
    for (int o = 1; o < 64; o <<= 1) gmin = fminf(gmin, __shfl_xor(gmin, o));
    const float thr = gmin + W_COEF * sqrtf(xn * enmax[0]) + W_GUARD;

    uint64 qual = __ballot(m <= thr);
    float bestd = 3.4e38f;
    int   besti = 0x7FFFFFFF;

    auto eval = [&](int c) {
        const float4* e4 = (const float4*)(cb + (size_t)c * DIM);
        const float4 ea = e4[lane], eb = e4[lane + 64];
        float dot = xa.x * ea.x + xa.y * ea.y + xa.z * ea.z + xa.w * ea.w
                  + xb.x * eb.x + xb.y * eb.y + xb.z * eb.z + xb.w * eb.w;
        #pragma unroll
        for (int o = 1; o < 64; o <<= 1) dot += __shfl_xor(dot, o);
        const float D = xn + enorm[c] - 2.0f * dot;
        if (D < bestd || (D == bestd && c < besti)) { bestd = D; besti = c; }
    };

    while (qual) {
        const int s = __builtin_ctzll(qual); qual &= qual - 1;
        const uint64* mp = masks + ((size_t)row * 64 + s) * 2;
        uint64 mm0 = mp[0], mm1 = mp[1];
        const int cb0 = s * 128;
        while (mm0) { int b = __builtin_ctzll(mm0); mm0 &= mm0 - 1; eval(cb0 + b); }
        while (mm1) { int b = __builtin_ctzll(mm1); mm1 &= mm1 - 1; eval(cb0 + 64 + b); }
    }
    int idx = besti;
    if ((unsigned)idx >= NCODE) idx = 0;      // safety: no wild gather
    if (lane == 0) out_idx[row] = (float)idx;

    // ---- finish: gather e, write qout, exact ||x-e||^2 -> mind + lpart ----
    const float4* e4 = (const float4*)(cb + (size_t)idx * DIM);
    float4* q4 = (float4*)(qout + (size_t)row * DIM);
    const float4 ea = e4[lane], eb = e4[lane + 64];
    q4[lane]      = ea;
    q4[lane + 64] = eb;
    float dx0 = xa.x - ea.x, dy0 = xa.y - ea.y, dz0 = xa.z - ea.z, dw0 = xa.w - ea.w;
    float dx1 = xb.x - eb.x, dy1 = xb.y - eb.y, dz1 = xb.z - eb.z, dw1 = xb.w - eb.w;
    float s = dx0 * dx0 + dy0 * dy0 + dz0 * dz0 + dw0 * dw0
            + dx1 * dx1 + dy1 * dy1 + dz1 * dz1 + dw1 * dw1;
    #pragma unroll
    for (int o = 32; o > 0; o >>= 1) s += __shfl_down(s, o);
    if (lane == 0) { sred[wave] = s; out_mind[row] = s; }
    __syncthreads();
    if (threadIdx.x == 0)
        lpart[blockIdx.x] = sred[0] + sred[1] + sred[2] + sred[3];
}

// ===========================================================================
// Kernel 4: final loss. loss_vq == loss_commit numerically => loss = 1.25*commit
__global__ __launch_bounds__(256) void loss_kernel(const float* __restrict__ lpart,
                                                   float* __restrict__ out_loss,
                                                   float* __restrict__ out_commit) {
    __shared__ float sm[256];
    float s = 0.0f;
    for (int i = threadIdx.x; i < 2048; i += 256) s += lpart[i];
    sm[threadIdx.x] = s;
    __syncthreads();
    #pragma unroll
    for (int o = 128; o > 0; o >>= 1) {
        if (threadIdx.x < o) sm[threadIdx.x] += sm[threadIdx.x + o];
        __syncthreads();
    }
    if (threadIdx.x == 0) {
        *out_commit = sm[0];
        *out_loss   = 1.25f * sm[0];
    }
}

// ===========================================================================
extern "C" void kernel_launch(void* const* d_in, const int* in_sizes, int n_in,
                              void* d_out, int out_size, void* d_ws, size_t ws_size,
                              hipStream_t stream) {
    const float* x  = (const float*)d_in[0];
    const float* cb = (const float*)d_in[1];
    float* out = (float*)d_out;
    float* ws  = (float*)d_ws;

    // ahi in d_out 1st half; masks in d_out 2nd half (both dead before the
    // refine kernel's qout writes land)
    ushort_t* ahi   = (ushort_t*)d_out;
    uint64*   masks = (uint64*)(out + 2097152);
    ushort_t* bhi   = (ushort_t*)(ws + WS_BHI);
    float* xnorm = ws + WS_XNORM;
    float* enorm = ws + WS_ENORM;
    float* enmax = ws + WS_ENMAX;
    float* mins  = ws + WS_MINS;
    float* lpart = ws + WS_LPART;

    conv_kernel<<<4096, 256, 0, stream>>>(x, cb, ahi, bhi, xnorm, enorm);
    prep_kernel<<<1, 256, 0, stream>>>(enorm, enmax);
    vq_mfma_kernel<<<2048, 256, 0, stream>>>(ahi, bhi, xnorm, enorm, enmax,
                                             mins, masks);
    refine_kernel<<<2048, 256, 0, stream>>>(x, cb, xnorm, enorm, enmax,
                                            mins, masks, out + OUT_IDX,
                                            out + OUT_Q, out + OUT_MIND, lpart);
    loss_kernel<<<1, 256, 0, stream>>>(lpart, out + OUT_LOSS, out + OUT_COMMIT);
}

// Round 9
// 227.993 us; speedup vs baseline: 4.0317x; 4.0317x over previous
//
#include <hip/hip_runtime.h>

typedef __attribute__((ext_vector_type(8)))  short short8;   // 8 bf16 (4 VGPRs)
typedef __attribute__((ext_vector_type(16))) float f32x16;   // 32x32 MFMA acc
typedef unsigned short ushort_t;
typedef unsigned int uint32;
typedef unsigned long long uint64;

#define NROWS 8192
#define NCODE 8192
#define DIM   512

// error window: |(d'+xn) - D| <= 2*2.004*2^-8*sqrt(xn*enmax)  (bf16 RNE + C-S)
// W = 2x that + guard (covers fp32 epilogue rounding)
#define W_COEF  0.032f
#define W_GUARD 0.6f

// ---------------- d_out layout (floats) ----------------
#define OUT_Q      0
#define OUT_LOSS   4194304
#define OUT_IDX    4194305
#define OUT_MIND   4202497
#define OUT_COMMIT 4210689
// masks[8192][64][2] u64 live in d_out floats [2097152, 4194304) between
// vq (write) and refine (read). NOTE (R9, the R7/R8 bug): nothing may write
// d_out[0, 4194304) while refine runs -- qout gather must be a SEPARATE
// kernel after refine (kernel boundary), else qout clobbers other blocks'
// masks mid-read. ahi (d_out 1st half) is dead after vq.

// ---------------- ws layout (floats) ----------------
#define WS_ENORM  0           // 8192
#define WS_XNORM  8192        // 8192
#define WS_ENMAX  16384       // 1
#define WS_LPART  16448       // 2048
#define WS_MINS   32768       // mins[8192][64] f32 = 524288 floats
#define WS_BHI    557056      // 4,194,304 ushorts (8.39 MB)

// ===========================================================================
__device__ inline uint32 bf16_rne(float f) {
    uint32 u = __float_as_uint(f);
    return (u + 0x7FFFu + ((u >> 16) & 1u)) >> 16;
}

__device__ inline void gload16(const ushort_t* g, ushort_t* l) {
    __builtin_amdgcn_global_load_lds(
        (const __attribute__((address_space(1))) void*)g,
        (__attribute__((address_space(3))) void*)l, 16, 0, 0);
}

// ===========================================================================
// Kernel 1: convert x and codebook to fragment-ordered bf16 HI tiles only.
// Tile = 128 rows x 32 k, 8 KB, 8 chunks of 1 KB: chunk c = r32*2 + k16;
// lane L holds row = r32*32 + (L&31), k = k16*16 + (L>>5)*8 + j.
// Also exact fp32 row norms (xnorm for inputs, enorm for codebook).
__global__ __launch_bounds__(256) void conv_kernel(const float* __restrict__ x,
                                                   const float* __restrict__ cb,
                                                   ushort_t* __restrict__ ahi,
                                                   ushort_t* __restrict__ bhi,
                                                   float* __restrict__ xnorm,
                                                   float* __restrict__ enorm) {
    int gid  = blockIdx.x * 256 + threadIdx.x;   // 0..1048575
    bool isA = gid < 524288;
    int g    = isA ? gid : gid - 524288;
    int row  = g >> 6;
    int lane = g & 63;
    int k0   = lane * 8;
    const float* src = (isA ? x : cb) + (size_t)row * DIM + k0;
    float v[8];
    *(float4*)&v[0] = *(const float4*)src;
    *(float4*)&v[4] = *(const float4*)(src + 4);
    float s = 0.0f;
    uint32 h[8];
    #pragma unroll
    for (int i = 0; i < 8; ++i) {
        s += v[i] * v[i];
        h[i] = bf16_rne(v[i]);
    }
    int tile = (row >> 7) * 16 + (k0 >> 5);
    int rp = row & 127, kp = k0 & 31;
    int c  = (rp >> 5) * 2 + (kp >> 4);
    int L  = (rp & 31) + (((kp >> 3) & 1) << 5);
    size_t off = (size_t)tile * 4096 + c * 512 + L * 8;   // ushort units
    uint4 ph;
    ph.x = h[0] | (h[1] << 16); ph.y = h[2] | (h[3] << 16);
    ph.z = h[4] | (h[5] << 16); ph.w = h[6] | (h[7] << 16);
    if (isA) *(uint4*)(ahi + off) = ph;
    else     *(uint4*)(bhi + off) = ph;
    #pragma unroll
    for (int o = 32; o > 0; o >>= 1) s += __shfl_down(s, o);
    if (lane == 0) { if (isA) xnorm[row] = s; else enorm[row] = s; }
}

// ===========================================================================
// Kernel 1b: en_max = max over codebook norms (for the prune bound).
__global__ __launch_bounds__(256) void prep_kernel(const float* __restrict__ enorm,
                                                   float* __restrict__ enmax) {
    __shared__ float sm[256];
    float m = 0.0f;
    for (int i = threadIdx.x; i < NCODE; i += 256) m = fmaxf(m, enorm[i]);
    sm[threadIdx.x] = m;
    __syncthreads();
    #pragma unroll
    for (int o = 128; o > 0; o >>= 1) {
        if (threadIdx.x < o) sm[threadIdx.x] = fmaxf(sm[threadIdx.x], sm[threadIdx.x + o]);
        __syncthreads();
    }
    if (threadIdx.x == 0) enmax[0] = sm[0];
}

// ===========================================================================
// Kernel 2 (unchanged from R8): hi-only GEMM, K-step 32, triple-buffered B
// LDS + A direct. Region-counted waits: each STEP issues exactly 6 vmem ops
// in one asm-clobber-bounded region; vmcnt(4) at step end => (in-order vmcnt
// retirement) everything from all PRIOR regions is complete, so buf(n+1) is
// landed before STEP(n+1) regardless of in-region load ordering. WAR on buf
// n%3 is protected by lgkmcnt(0) + s_barrier before its restage region.
// Block 256 rows x 128 cols, 4 waves row-stacked, wave tile 64x128 acc[2][4].
// Grid 2048 = 32 bx x 64 by; XCD q&7 hosts bx band (1 MB A L2-resident).
struct AF { short8 a00, a01, a10, a11; };   // a{ti}{p}

__global__ __launch_bounds__(256, 2) void vq_mfma_kernel(
        const ushort_t* __restrict__ ahi, const ushort_t* __restrict__ bhi,
        const float* __restrict__ xnorm, const float* __restrict__ enorm,
        const float* __restrict__ enmax,
        float* __restrict__ mins, uint64* __restrict__ masks) {
    __shared__ __align__(16) ushort_t smem[12288];   // 3 x 8 KB B buffers

    const int tid  = threadIdx.x;            // 0..255
    const int wave = tid >> 6, lane = tid & 63;
    const int l31  = lane & 31, half = lane >> 5;
    const int q  = blockIdx.x;
    const int bx = (q & 7) * 4 + (q >> 9);   // 0..31 (256-row block), XCD=q&7
    const int by = (q >> 3) & 63;            // 0..63 (128-col slice)
    const int l8 = lane * 8;

    f32x16 acc[2][4];
    #pragma unroll
    for (int i = 0; i < 2; ++i)
        #pragma unroll
        for (int j = 0; j < 4; ++j)
            #pragma unroll
            for (int r = 0; r < 16; ++r) acc[i][j][r] = 0.0f;

    // A row-tile base pointers: rt = bx*8 + wave*2 + ti
    // conv layout: addr(rt, kk) = (rt>>2)*65536 + (rt&3)*1024 + (kk>>1)*4096
    //                           + (kk&1)*512 + l8   (ushort units)
    const int rt0 = bx * 8 + wave * 2, rt1 = rt0 + 1;
    const ushort_t* pa0 = ahi + ((size_t)(rt0 >> 2)) * 65536 + (rt0 & 3) * 1024 + l8;
    const ushort_t* pa1 = ahi + ((size_t)(rt1 >> 2)) * 65536 + (rt1 & 3) * 1024 + l8;
    // B tile base: step n occupies [by*16+n]*4096 ushorts (full 8 KB tile)
    const ushort_t* pb = bhi + ((size_t)by * 16) * 4096;

    // stage B step nn into buffer nn%3 (8 KB, 2 gload16/thread)
    auto stageB = [&](int nn) {
        ushort_t* S = smem + (nn % 3) * 4096;
        gload16(pb + (size_t)nn * 4096 + tid * 8,        S + tid * 8);
        gload16(pb + (size_t)nn * 4096 + 2048 + tid * 8, S + 2048 + tid * 8);
    };
    auto loadA = [&](AF& F, int nn) {
        F.a00 = *(const short8*)(pa0 + (size_t)nn * 4096);
        F.a01 = *(const short8*)(pa0 + (size_t)nn * 4096 + 512);
        F.a10 = *(const short8*)(pa1 + (size_t)nn * 4096);
        F.a11 = *(const short8*)(pa1 + (size_t)nn * 4096 + 512);
    };

#define STEP(n, CUR, NXT) do {                                                \
    if ((n) + 1 < 16) loadA(NXT, (n) + 1);        /* 4 vmem */               \
    if ((n) + 2 < 16) stageB((n) + 2);            /* 2 vmem, buf (n+2)%3 */  \
    const ushort_t* S = smem + ((n) % 3) * 4096;                              \
    short8 b0 = *(const short8*)&S[0 * 1024 + l8];                            \
    short8 b1 = *(const short8*)&S[1 * 1024 + l8];                            \
    short8 b2 = *(const short8*)&S[2 * 1024 + l8];                            \
    short8 b3 = *(const short8*)&S[3 * 1024 + l8];                            \
    asm volatile("s_waitcnt lgkmcnt(0)" ::: "memory");                        \
    __builtin_amdgcn_sched_barrier(0);                                        \
    __builtin_amdgcn_s_setprio(1);                                            \
    acc[0][0] = __builtin_amdgcn_mfma_f32_32x32x16_bf16(CUR.a00, b0, acc[0][0], 0, 0, 0); \
    acc[0][1] = __builtin_amdgcn_mfma_f32_32x32x16_bf16(CUR.a00, b1, acc[0][1], 0, 0, 0); \
    acc[0][2] = __builtin_amdgcn_mfma_f32_32x32x16_bf16(CUR.a00, b2, acc[0][2], 0, 0, 0); \
    acc[0][3] = __builtin_amdgcn_mfma_f32_32x32x16_bf16(CUR.a00, b3, acc[0][3], 0, 0, 0); \
    acc[1][0] = __builtin_amdgcn_mfma_f32_32x32x16_bf16(CUR.a10, b0, acc[1][0], 0, 0, 0); \
    acc[1][1] = __builtin_amdgcn_mfma_f32_32x32x16_bf16(CUR.a10, b1, acc[1][1], 0, 0, 0); \
    acc[1][2] = __builtin_amdgcn_mfma_f32_32x32x16_bf16(CUR.a10, b2, acc[1][2], 0, 0, 0); \
    acc[1][3] = __builtin_amdgcn_mfma_f32_32x32x16_bf16(CUR.a10, b3, acc[1][3], 0, 0, 0); \
    __builtin_amdgcn_s_setprio(0);                                            \
    short8 c0 = *(const short8*)&S[0 * 1024 + 512 + l8];                      \
    short8 c1 = *(const short8*)&S[1 * 1024 + 512 + l8];                      \
    short8 c2 = *(const short8*)&S[2 * 1024 + 512 + l8];                      \
    short8 c3 = *(const short8*)&S[3 * 1024 + 512 + l8];                      \
    asm volatile("s_waitcnt lgkmcnt(0)" ::: "memory");                        \
    __builtin_amdgcn_sched_barrier(0);                                        \
    __builtin_amdgcn_s_setprio(1);                                            \
    acc[0][0] = __builtin_amdgcn_mfma_f32_32x32x16_bf16(CUR.a01, c0, acc[0][0], 0, 0, 0); \
    acc[0][1] = __builtin_amdgcn_mfma_f32_32x32x16_bf16(CUR.a01, c1, acc[0][1], 0, 0, 0); \
    acc[0][2] = __builtin_amdgcn_mfma_f32_32x32x16_bf16(CUR.a01, c2, acc[0][2], 0, 0, 0); \
    acc[0][3] = __builtin_amdgcn_mfma_f32_32x32x16_bf16(CUR.a01, c3, acc[0][3], 0, 0, 0); \
    acc[1][0] = __builtin_amdgcn_mfma_f32_32x32x16_bf16(CUR.a11, c0, acc[1][0], 0, 0, 0); \
    acc[1][1] = __builtin_amdgcn_mfma_f32_32x32x16_bf16(CUR.a11, c1, acc[1][1], 0, 0, 0); \
    acc[1][2] = __builtin_amdgcn_mfma_f32_32x32x16_bf16(CUR.a11, c2, acc[1][2], 0, 0, 0); \
    acc[1][3] = __builtin_amdgcn_mfma_f32_32x32x16_bf16(CUR.a11, c3, acc[1][3], 0, 0, 0); \
    __builtin_amdgcn_s_setprio(0);                                            \
    /* region-counted wait: <=4 outstanding => ALL prior regions complete */  \
    if ((n) + 2 < 16) { asm volatile("s_waitcnt vmcnt(4)" ::: "memory"); }    \
    else              { asm volatile("s_waitcnt vmcnt(0)" ::: "memory"); }    \
    asm volatile("s_barrier" ::: "memory");                                   \
} while (0)

    AF FA, FB;
    // prologue: order-free full drain (one-time), then region-pipelined loop
    stageB(0);
    stageB(1);
    loadA(FA, 0);
    asm volatile("s_waitcnt vmcnt(0)" ::: "memory");   // buf0, buf1, FA landed
    asm volatile("s_barrier" ::: "memory");

    #pragma unroll
    for (int n = 0; n < 16; ++n) {
        if (n & 1) STEP(n, FB, FA);
        else       STEP(n, FA, FB);
    }
#undef STEP

    // ---- epilogue: per row emit f32 slice-min + 128-bit candidate mask ----
    const float enm = enmax[0];
    float en[4];
    #pragma unroll
    for (int tj = 0; tj < 4; ++tj) en[tj] = enorm[by * 128 + tj * 32 + l31];

    #pragma unroll
    for (int ti = 0; ti < 2; ++ti)
        #pragma unroll
        for (int r = 0; r < 16; ++r) {
            const int row = bx * 256 + wave * 64 + ti * 32
                          + (r & 3) + 8 * (r >> 2) + 4 * half;
            const float xn = xnorm[row];
            const float W  = W_COEF * sqrtf(xn * enm) + W_GUARD;
            const float d0 = en[0] - 2.0f * acc[ti][0][r];
            const float d1 = en[1] - 2.0f * acc[ti][1][r];
            const float d2 = en[2] - 2.0f * acc[ti][2][r];
            const float d3 = en[3] - 2.0f * acc[ti][3][r];
            float m = fminf(fminf(d0, d1), fminf(d2, d3));
            #pragma unroll
            for (int o = 1; o < 32; o <<= 1) m = fminf(m, __shfl_xor(m, o));
            const float t = m + W;
            const uint64 b0m = __ballot(d0 <= t);
            const uint64 b1m = __ballot(d1 <= t);
            const uint64 b2m = __ballot(d2 <= t);
            const uint64 b3m = __ballot(d3 <= t);
            if (l31 == 0) {
                const int sh = half * 32;
                const uint64 m0 = ((b0m >> sh) & 0xFFFFFFFFull)
                                | (((b1m >> sh) & 0xFFFFFFFFull) << 32);
                const uint64 m1 = ((b2m >> sh) & 0xFFFFFFFFull)
                                | (((b3m >> sh) & 0xFFFFFFFFull) << 32);
                const size_t rec = (size_t)row * 64 + by;
                mins[rec] = m;
                masks[rec * 2]     = m0;
                masks[rec * 2 + 1] = m1;
            }
        }
}

// ===========================================================================
// Kernel 3 (R9): refine, idx ONLY. Per row (one wave): gmin over 64 slice
// mins; window thr = gmin + W; exact fp32 wave-coop distance for each
// candidate column from the ballot masks (~3-8/row). Writes out_idx and
// NOTHING else in d_out (masks stay intact while other blocks run).
__global__ __launch_bounds__(256) void refine_kernel(
        const float* __restrict__ x, const float* __restrict__ cb,
        const float* __restrict__ xnorm, const float* __restrict__ enorm,
        const float* __restrict__ enmax, const float* __restrict__ mins,
        const uint64* __restrict__ masks, float* __restrict__ out_idx) {
    const int wave = threadIdx.x >> 6, lane = threadIdx.x & 63;
    const int row  = blockIdx.x * 4 + wave;

    const float4* x4 = (const float4*)(x + (size_t)row * DIM);
    const float4 xa = x4[lane], xb = x4[lane + 64];
    const float  xn = xnorm[row];

    float m = mins[(size_t)row * 64 + lane];
    float gmin = m;
    #pragma unroll
    for (int o = 1; o < 64; o <<= 1) gmin = fminf(gmin, __shfl_xor(gmin, o));
    const float thr = gmin + W_COEF * sqrtf(xn * enmax[0]) + W_GUARD;

    uint64 qual = __ballot(m <= thr);
    float bestd = 3.4e38f;
    int   besti = 0x7FFFFFFF;

    auto eval = [&](int c) {
        const float4* e4 = (const float4*)(cb + (size_t)c * DIM);
        const float4 ea = e4[lane], eb = e4[lane + 64];
        float dot = xa.x * ea.x + xa.y * ea.y + xa.z * ea.z + xa.w * ea.w
                  + xb.x * eb.x + xb.y * eb.y + xb.z * eb.z + xb.w * eb.w;
        #pragma unroll
        for (int o = 1; o < 64; o <<= 1) dot += __shfl_xor(dot, o);
        const float D = xn + enorm[c] - 2.0f * dot;
        if (D < bestd || (D == bestd && c < besti)) { bestd = D; besti = c; }
    };

    while (qual) {
        const int s = __builtin_ctzll(qual); qual &= qual - 1;
        const uint64* mp = masks + ((size_t)row * 64 + s) * 2;
        uint64 mm0 = mp[0], mm1 = mp[1];
        const int cb0 = s * 128;
        while (mm0) { int b = __builtin_ctzll(mm0); mm0 &= mm0 - 1; eval(cb0 + b); }
        while (mm1) { int b = __builtin_ctzll(mm1); mm1 &= mm1 - 1; eval(cb0 + 64 + b); }
    }
    int idx = besti;
    if ((unsigned)idx >= NCODE) idx = 0;      // safety: no wild gather
    if (lane == 0) out_idx[row] = (float)idx;
}

// ===========================================================================
// Kernel 4 (R6's proven finish, separate kernel AFTER refine): gather
// codebook row -> qout, exact fp32 ||x-e||^2 -> mind + loss partials.
// Runs after refine completes, so overwriting the masks region is safe.
__global__ __launch_bounds__(256) void finish_kernel(const float* __restrict__ x,
                                                     const float* __restrict__ cb,
                                                     const float* __restrict__ out_idx,
                                                     float* __restrict__ qout,
                                                     float* __restrict__ out_mind,
                                                     float* __restrict__ lpart) {
    __shared__ float sred[4];
    int row  = blockIdx.x * 4 + (threadIdx.x >> 6);
    int lane = threadIdx.x & 63;
    int idx  = (int)out_idx[row];

    const float4* e4 = (const float4*)(cb + (size_t)idx * DIM);
    const float4* x4 = (const float4*)(x + (size_t)row * DIM);
    float4* q4 = (float4*)(qout + (size_t)row * DIM);
    float s = 0.0f;
    #pragma unroll
    for (int u = 0; u < 2; ++u) {
        float4 e  = e4[lane + u * 64];
        float4 xv = x4[lane + u * 64];
        q4[lane + u * 64] = e;
        float dx = xv.x - e.x, dy = xv.y - e.y, dz = xv.z - e.z, dw = xv.w - e.w;
        s += dx * dx + dy * dy + dz * dz + dw * dw;
    }
    #pragma unroll
    for (int o = 32; o > 0; o >>= 1) s += __shfl_down(s, o);
    if (lane == 0) { sred[threadIdx.x >> 6] = s; out_mind[row] = s; }
    __syncthreads();
    if (threadIdx.x == 0)
        lpart[blockIdx.x] = sred[0] + sred[1] + sred[2] + sred[3];
}

// ===========================================================================
// Kernel 5: final loss. loss_vq == loss_commit numerically => loss = 1.25*commit
__global__ __launch_bounds__(256) void loss_kernel(const float* __restrict__ lpart,
                                                   float* __restrict__ out_loss,
                                                   float* __restrict__ out_commit) {
    __shared__ float sm[256];
    float s = 0.0f;
    for (int i = threadIdx.x; i < 2048; i += 256) s += lpart[i];
    sm[threadIdx.x] = s;
    __syncthreads();
    #pragma unroll
    for (int o = 128; o > 0; o >>= 1) {
        if (threadIdx.x < o) sm[threadIdx.x] += sm[threadIdx.x + o];
        __syncthreads();
    }
    if (threadIdx.x == 0) {
        *out_commit = sm[0];
        *out_loss   = 1.25f * sm[0];
    }
}

// ===========================================================================
extern "C" void kernel_launch(void* const* d_in, const int* in_sizes, int n_in,
                              void* d_out, int out_size, void* d_ws, size_t ws_size,
                              hipStream_t stream) {
    const float* x  = (const float*)d_in[0];
    const float* cb = (const float*)d_in[1];
    float* out = (float*)d_out;
    float* ws  = (float*)d_ws;

    // ahi in d_out 1st half; masks in d_out 2nd half. Both are dead only
    // AFTER refine completes; finish (separate launch) then reuses d_out
    // for qout.
    ushort_t* ahi   = (ushort_t*)d_out;
    uint64*   masks = (uint64*)(out + 2097152);
    ushort_t* bhi   = (ushort_t*)(ws + WS_BHI);
    float* xnorm = ws + WS_XNORM;
    float* enorm = ws + WS_ENORM;
    float* enmax = ws + WS_ENMAX;
    float* mins  = ws + WS_MINS;
    float* lpart = ws + WS_LPART;

    conv_kernel<<<4096, 256, 0, stream>>>(x, cb, ahi, bhi, xnorm, enorm);
    prep_kernel<<<1, 256, 0, stream>>>(enorm, enmax);
    vq_mfma_kernel<<<2048, 256, 0, stream>>>(ahi, bhi, xnorm, enorm, enmax,
                                             mins, masks);
    refine_kernel<<<2048, 256, 0, stream>>>(x, cb, xnorm, enorm, enmax,
                                            mins, masks, out + OUT_IDX);
    finish_kernel<<<2048, 256, 0, stream>>>(x, cb, out + OUT_IDX, out + OUT_Q,
                                            out + OUT_MIND, lpart);
    loss_kernel<<<1, 256, 0, stream>>>(lpart, out + OUT_LOSS, out + OUT_COMMIT);
}